// Round 1
// baseline (264.763 us; speedup 1.0000x reference)
//
#include <hip/hip_runtime.h>
#include <math.h>

#define B_   2
#define C_   8
#define NB_  3
#define X_   80
#define Y_   80
#define M_   4096
#define P_   (X_*Y_)      // 6400
#define NJ   (C_*NB_)     // 24 columns, j = c*NB_ + nb
#define BM   32           // m per block
#define S_   2            // k-split across blocks
#define TPB  256

// ---------------- kernel 1: cimgT[b][p][j] = maps[b,c,nb,p] * x[b,nb,p] (complex)
__global__ void prep_cimg(const float* __restrict__ x, const float* __restrict__ maps,
                          float* __restrict__ cimgT) {
  int tid = blockIdx.x * blockDim.x + threadIdx.x;   // (b*NJ + j)*P + p
  if (tid >= B_ * NJ * P_) return;
  int p  = tid % P_;
  int bj = tid / P_;
  int j  = bj % NJ;
  int b  = bj / NJ;
  int c  = j / NB_, nb = j % NB_;
  const float* xp = x    + (((size_t)b*NB_ + nb)*P_ + p)*2;
  const float* mp = maps + ((((size_t)b*C_ + c)*NB_ + nb)*P_ + p)*2;
  float xr = xp[0], xi = xp[1], mr = mp[0], mi = mp[1];
  float* o = cimgT + (((size_t)b*P_ + p)*NJ + j)*2;
  o[0] = mr*xr - mi*xi;
  o[1] = mr*xi + mi*xr;
}

// ---------------- kernel 2: main tall-skinny complex GEMM with on-the-fly E
__global__ __launch_bounds__(TPB) void main_gemm(
    const float* __restrict__ coord, const float* __restrict__ cimgT,
    const float* __restrict__ phi, float* __restrict__ partial) {
  __shared__ float smem[2 * BM * X_ * 2];      // 10240 floats = 40 KB
  float2* exs = (float2*)smem;                 // [X_][BM], includes 1/80 norm
  float2* eys = exs + BM * X_;                 // [Y_][BM]

  int mtile = blockIdx.x, kc = blockIdx.y, b = blockIdx.z;
  int m0 = mtile * BM;
  int tid = threadIdx.x;

  // Build ex/ey tables: exp(-2*pi*i * coord * (g-40)/80)
  for (int i = tid; i < 2 * BM * X_; i += TPB) {
    int table = i / (BM * X_);         // 0 -> ex (coord0), 1 -> ey (coord1)
    int r  = i % (BM * X_);
    int ml = r / X_;
    int g  = r % X_;
    float cc = coord[((size_t)b*M_ + (m0 + ml))*2 + table];
    float t  = cc * (float)(g - X_/2) * (1.0f / X_);
    float s, co;
    __sincosf(-6.28318530717958647692f * t, &s, &co);
    float sc = table ? 1.0f : (1.0f / 80.0f);
    (table ? eys : exs)[g*BM + ml] = make_float2(co * sc, s * sc);
  }
  __syncthreads();

  int ks = tid >> 5;        // k-slice 0..7
  int w  = tid & 31;
  int cg = w >> 3;          // col group 0..3 (6 cols each)
  int mg = w & 7;           // m group 0..7 (4 m each)

  const float2* cbase = (const float2*)cimgT + (size_t)b * P_ * NJ + cg * 6;

  float2 acc[4][6];
  #pragma unroll
  for (int a = 0; a < 4; a++)
    #pragma unroll
    for (int jj = 0; jj < 6; jj++) acc[a][jj] = make_float2(0.f, 0.f);

  int x0 = kc * (X_ / S_) + ks * (X_ / S_ / 8);   // 5 x-rows per k-slice
  for (int xi = 0; xi < X_ / S_ / 8; ++xi) {
    int xx = x0 + xi;
    float2 exv[4];
    #pragma unroll
    for (int mi = 0; mi < 4; mi++) exv[mi] = exs[xx*BM + mg*4 + mi];

    float2 t[4][6];
    #pragma unroll
    for (int a = 0; a < 4; a++)
      #pragma unroll
      for (int jj = 0; jj < 6; jj++) t[a][jj] = make_float2(0.f, 0.f);

    const float2* cp = cbase + (size_t)xx * Y_ * NJ;
    for (int y = 0; y < Y_; ++y, cp += NJ) {
      float2 eyv[4];
      #pragma unroll
      for (int mi = 0; mi < 4; mi++) eyv[mi] = eys[y*BM + mg*4 + mi];
      float4 q0 = *(const float4*)(cp + 0);
      float4 q1 = *(const float4*)(cp + 2);
      float4 q2 = *(const float4*)(cp + 4);
      float2 cv[6] = { make_float2(q0.x,q0.y), make_float2(q0.z,q0.w),
                       make_float2(q1.x,q1.y), make_float2(q1.z,q1.w),
                       make_float2(q2.x,q2.y), make_float2(q2.z,q2.w) };
      #pragma unroll
      for (int mi = 0; mi < 4; mi++)
        #pragma unroll
        for (int jj = 0; jj < 6; jj++) {
          t[mi][jj].x = fmaf(eyv[mi].x, cv[jj].x, fmaf(-eyv[mi].y, cv[jj].y, t[mi][jj].x));
          t[mi][jj].y = fmaf(eyv[mi].x, cv[jj].y, fmaf( eyv[mi].y, cv[jj].x, t[mi][jj].y));
        }
    }
    #pragma unroll
    for (int mi = 0; mi < 4; mi++)
      #pragma unroll
      for (int jj = 0; jj < 6; jj++) {
        acc[mi][jj].x = fmaf(exv[mi].x, t[mi][jj].x, fmaf(-exv[mi].y, t[mi][jj].y, acc[mi][jj].x));
        acc[mi][jj].y = fmaf(exv[mi].x, t[mi][jj].y, fmaf( exv[mi].y, t[mi][jj].x, acc[mi][jj].y));
      }
  }

  // ---- reduce the 8 k-slices: butterfly across lane^32, then LDS across waves
  float* af = (float*)acc;   // 48 floats
  #pragma unroll
  for (int k = 0; k < 48; k++) af[k] += __shfl_xor(af[k], 32);

  int wv = tid >> 6;       // wave 0..3
  int ln = tid & 63;
  __syncthreads();         // done with exs/eys, reuse smem
  float* red = smem;       // [3][32][48] = 4608 floats
  if (wv > 0 && ln < 32) {
    float* rp = red + ((wv - 1) * 32 + ln) * 48;
    #pragma unroll
    for (int k = 0; k < 48; k++) rp[k] = af[k];
  }
  __syncthreads();

  if (tid < 32) {          // wv==0, ln==w: mg = tid&7, cg = tid>>3
    #pragma unroll
    for (int r = 0; r < 3; r++) {
      float* rp = red + (r * 32 + tid) * 48;
      #pragma unroll
      for (int k = 0; k < 48; k++) af[k] += rp[k];
    }
    // apply phi and write this k-chunk's partial
    #pragma unroll
    for (int mi = 0; mi < 4; mi++) {
      int m = m0 + mg*4 + mi;
      const float* php = phi + ((size_t)b*NB_*M_ + m)*2;
      float2 ph[3];
      #pragma unroll
      for (int nb = 0; nb < 3; nb++) ph[nb] = *(const float2*)(php + (size_t)nb*M_*2);
      #pragma unroll
      for (int cc = 0; cc < 2; cc++) {
        int c = cg*2 + cc;
        float2 o = make_float2(0.f, 0.f);
        #pragma unroll
        for (int nb = 0; nb < 3; nb++) {
          float2 kk = acc[mi][cc*3 + nb];
          o.x += ph[nb].x*kk.x - ph[nb].y*kk.y;
          o.y += ph[nb].x*kk.y + ph[nb].y*kk.x;
        }
        float* op = partial + (((((size_t)kc*B_ + b)*C_ + c)*M_) + m)*2;
        *(float2*)op = o;
      }
    }
  }
}

// ---------------- kernel 3: sum the S_ k-chunk partials
__global__ void combine(const float* __restrict__ partial, float* __restrict__ out, int n) {
  int i = blockIdx.x * blockDim.x + threadIdx.x;
  if (i < n) {
    float v = partial[i];
    #pragma unroll
    for (int s = 1; s < S_; s++) v += partial[(size_t)s*n + i];
    out[i] = v;
  }
}

extern "C" void kernel_launch(void* const* d_in, const int* in_sizes, int n_in,
                              void* d_out, int out_size, void* d_ws, size_t ws_size,
                              hipStream_t stream) {
  const float* x     = (const float*)d_in[0];
  const float* maps  = (const float*)d_in[1];
  const float* phi   = (const float*)d_in[2];
  const float* coord = (const float*)d_in[3];
  float* out = (float*)d_out;
  float* ws  = (float*)d_ws;

  float* cimgT   = ws;                              // B*P*NJ*2 = 614400 floats
  float* partial = ws + (size_t)B_*P_*NJ*2;         // S_*B*C*M*2 = 262144 floats

  {
    int total = B_ * NJ * P_;
    prep_cimg<<<(total + 255)/256, 256, 0, stream>>>(x, maps, cimgT);
  }
  {
    dim3 g2(M_ / BM, S_, B_);
    main_gemm<<<g2, TPB, 0, stream>>>(coord, cimgT, phi, partial);
  }
  {
    int n = B_ * C_ * M_ * 2;                       // 131072
    combine<<<(n + 255)/256, 256, 0, stream>>>(partial, out, n);
  }
}

// Round 2
// 39.928 us; speedup vs baseline: 6.6310x; 6.6310x over previous
//
#include <hip/hip_runtime.h>
#include <hip/hip_fp16.h>
#include <math.h>

#define B_   2
#define C_   8
#define NB_  3
#define X_   80
#define Y_   80
#define M_   4096
#define P_   6400
#define NJ   24
#define KS   3          // k-steps of 32 (y padded 80->96)
#define NF   2          // n-frags (j padded 24->32)
#define TWO_PI 6.2831853071795864769f

typedef _Float16 f16x8 __attribute__((ext_vector_type(8)));
typedef float    f32x4 __attribute__((ext_vector_type(4)));

// slot -> k mapping used consistently for BOTH A and B fragments (any consistent
// bijection is correct; hardware pairs identical slots of A and B).
__device__ __forceinline__ int klocal(int lane, int i) {
  return ((lane >> 4) << 2) + (i & 3) + ((i >> 2) << 4);
}

// ---------- kernel 1: cimg = maps*x, written in MFMA-fragment-ready f16 order.
// Bf layout (f16 units): (b*80+x)*6144 + (ks*2+nf)*1024 + {0:re,512:im} + lane*8 + i
__global__ void prep_bfrag(const float* __restrict__ xin, const float* __restrict__ maps,
                           _Float16* __restrict__ Bf) {
  int t = blockIdx.x * blockDim.x + threadIdx.x;
  if (t >= B_*X_*KS*NF*64*8) return;
  int i    = t & 7;
  int lane = (t >> 3) & 63;
  int nf   = (t >> 9) & 1;
  int rest = t >> 10;
  int ks   = rest % 3; rest /= 3;
  int x    = rest % 80;
  int b    = rest / 80;

  int j = nf*16 + (lane & 15);
  int y = ks*32 + klocal(lane, i);
  float re = 0.f, im = 0.f;
  if (y < Y_ && j < NJ) {
    int c = j / 3, nb = j % 3;
    int p = x*Y_ + y;
    const float* xp = xin  + (((size_t)b*NB_ + nb)*P_ + p)*2;
    const float* mp = maps + ((((size_t)b*C_ + c)*NB_ + nb)*P_ + p)*2;
    float xr = xp[0], xi2 = xp[1], mr = mp[0], mi = mp[1];
    re = mr*xr - mi*xi2;
    im = mr*xi2 + mi*xr;
  }
  size_t base = (size_t)((b*X_ + x)*6 + (ks*2 + nf)) * 1024;
  Bf[base + lane*8 + i]       = (_Float16)re;
  Bf[base + 512 + lane*8 + i] = (_Float16)im;
}

// ---------- kernel 2: per x: T = ey * cimg_x (MFMA over y), out += ex(m,x)*T
__global__ __launch_bounds__(256, 2) void main_mfma(
    const float* __restrict__ coord, const _Float16* __restrict__ Bf,
    float* __restrict__ partial, int XS, int xpb) {
  __shared__ unsigned int extab[X_ * 128];   // packed half2(cos,sin), [x][m_local]

  int mb   = blockIdx.x;          // 32 m-tiles of 128
  int xs   = blockIdx.y;          // x-split
  int b    = blockIdx.z;
  int tid  = threadIdx.x;
  int wave = tid >> 6, lane = tid & 63;
  int mblock = mb * 128;

  // ex table: exp(-2*pi*i * coord0 * (x-40)/80), f16 pair
  for (int t = tid; t < X_*128; t += 256) {
    int x = t >> 7, ml = t & 127;
    float c0 = coord[((size_t)b*M_ + mblock + ml)*2 + 0];
    float s, c;
    __sincosf(-TWO_PI * c0 * (float)(x - 40) * (1.0f/80.0f), &s, &c);
    __half2 h = __floats2half2_rn(c, s);
    extab[t] = *(unsigned int*)&h;
  }

  // ey A-fragments (loop-invariant, includes 1/80 norm); ain = -ai for the
  // Tr = Ar*Br - Ai*Bi combo.
  int mtile = mblock + wave*32;
  f16x8 ar[2][KS], ai[2][KS], ain[2][KS];
  #pragma unroll
  for (int mf = 0; mf < 2; mf++) {
    float c1 = coord[((size_t)b*M_ + mtile + mf*16 + (lane & 15))*2 + 1];
    #pragma unroll
    for (int ks = 0; ks < KS; ks++)
      #pragma unroll
      for (int i = 0; i < 8; i++) {
        int y = ks*32 + klocal(lane, i);
        float re = 0.f, im = 0.f;
        if (y < Y_) {
          float s, c;
          __sincosf(-TWO_PI * c1 * (float)(y - 40) * (1.0f/80.0f), &s, &c);
          re = c * (1.0f/80.0f); im = s * (1.0f/80.0f);
        }
        ar[mf][ks][i]  = (_Float16)re;
        ai[mf][ks][i]  = (_Float16)im;
        ain[mf][ks][i] = (_Float16)(-im);
      }
  }
  __syncthreads();

  f32x4 outr[2][NF], outi[2][NF];
  #pragma unroll
  for (int mf = 0; mf < 2; mf++)
    #pragma unroll
    for (int nf = 0; nf < NF; nf++) {
      outr[mf][nf] = (f32x4){0.f,0.f,0.f,0.f};
      outi[mf][nf] = (f32x4){0.f,0.f,0.f,0.f};
    }

  for (int xi = 0; xi < xpb; xi++) {
    int x = xs*xpb + xi;
    const _Float16* fb = Bf + (size_t)(b*X_ + x) * 6144;
    f16x8 br[KS][NF], bi[KS][NF];
    #pragma unroll
    for (int ks = 0; ks < KS; ks++)
      #pragma unroll
      for (int nf = 0; nf < NF; nf++) {
        const _Float16* p = fb + (ks*2 + nf)*1024 + lane*8;
        br[ks][nf] = *(const f16x8*)p;
        bi[ks][nf] = *(const f16x8*)(p + 512);
      }

    f32x4 Tr[2][NF], Ti[2][NF];
    #pragma unroll
    for (int mf = 0; mf < 2; mf++)
      #pragma unroll
      for (int nf = 0; nf < NF; nf++) {
        Tr[mf][nf] = (f32x4){0.f,0.f,0.f,0.f};
        Ti[mf][nf] = (f32x4){0.f,0.f,0.f,0.f};
      }

    #pragma unroll
    for (int ks = 0; ks < KS; ks++)
      #pragma unroll
      for (int mf = 0; mf < 2; mf++)
        #pragma unroll
        for (int nf = 0; nf < NF; nf++) {
          Tr[mf][nf] = __builtin_amdgcn_mfma_f32_16x16x32_f16(ar[mf][ks],  br[ks][nf], Tr[mf][nf], 0, 0, 0);
          Tr[mf][nf] = __builtin_amdgcn_mfma_f32_16x16x32_f16(ain[mf][ks], bi[ks][nf], Tr[mf][nf], 0, 0, 0);
          Ti[mf][nf] = __builtin_amdgcn_mfma_f32_16x16x32_f16(ar[mf][ks],  bi[ks][nf], Ti[mf][nf], 0, 0, 0);
          Ti[mf][nf] = __builtin_amdgcn_mfma_f32_16x16x32_f16(ai[mf][ks],  br[ks][nf], Ti[mf][nf], 0, 0, 0);
        }

    // epilogue: out += ex(m,x) * T   (ex reads are broadcast, bank-conflict-free)
    #pragma unroll
    for (int mf = 0; mf < 2; mf++)
      #pragma unroll
      for (int r = 0; r < 4; r++) {
        int ml = wave*32 + mf*16 + ((lane >> 4) << 2) + r;
        unsigned int u = extab[x*128 + ml];
        __half2 h = *(__half2*)&u;
        float exr = __low2float(h), exi = __high2float(h);
        #pragma unroll
        for (int nf = 0; nf < NF; nf++) {
          float tr = Tr[mf][nf][r], ti = Ti[mf][nf][r];
          outr[mf][nf][r] += exr*tr - exi*ti;
          outi[mf][nf][r] += exr*ti + exi*tr;
        }
      }
  }

  // write per-xsplit partial ksp: [xs][b][m][j]{re,im}
  #pragma unroll
  for (int mf = 0; mf < 2; mf++)
    #pragma unroll
    for (int nf = 0; nf < NF; nf++) {
      int j = nf*16 + (lane & 15);
      if (j < NJ) {
        #pragma unroll
        for (int r = 0; r < 4; r++) {
          int m = mtile + mf*16 + ((lane >> 4) << 2) + r;
          size_t o = ((((size_t)xs*B_ + b)*M_ + m)*NJ + j)*2;
          partial[o]   = outr[mf][nf][r];
          partial[o+1] = outi[mf][nf][r];
        }
      }
    }
}

// ---------- kernel 3: sum x-splits, apply phi, band-sum
__global__ void combine2(const float* __restrict__ partial, const float* __restrict__ phi,
                         float* __restrict__ out, int XS) {
  int t = blockIdx.x * blockDim.x + threadIdx.x;   // (b, m, c), c fastest
  if (t >= B_*M_*C_) return;
  int c = t & 7;
  int m = (t >> 3) & (M_ - 1);
  int b = t >> 15;
  float sr[3] = {0,0,0}, si[3] = {0,0,0};
  for (int xs = 0; xs < XS; xs++) {
    const float* p = partial + ((((size_t)xs*B_ + b)*M_ + m)*NJ + c*3)*2;
    #pragma unroll
    for (int nb = 0; nb < 3; nb++) { sr[nb] += p[nb*2]; si[nb] += p[nb*2+1]; }
  }
  float ox = 0.f, oy = 0.f;
  #pragma unroll
  for (int nb = 0; nb < 3; nb++) {
    const float* pp = phi + (((size_t)b*NB_ + nb)*M_ + m)*2;
    float pr = pp[0], pi = pp[1];
    ox += pr*sr[nb] - pi*si[nb];
    oy += pr*si[nb] + pi*sr[nb];
  }
  float* op = out + ((size_t)(b*C_ + c)*M_ + m)*2;
  op[0] = ox; op[1] = oy;
}

extern "C" void kernel_launch(void* const* d_in, const int* in_sizes, int n_in,
                              void* d_out, int out_size, void* d_ws, size_t ws_size,
                              hipStream_t stream) {
  const float* xin   = (const float*)d_in[0];
  const float* maps  = (const float*)d_in[1];
  const float* phi   = (const float*)d_in[2];
  const float* coord = (const float*)d_in[3];
  float* out = (float*)d_out;

  const size_t bf_bytes = (size_t)B_ * X_ * 6144 * sizeof(_Float16);   // 1.97 MB
  _Float16* Bf = (_Float16*)d_ws;
  auto need = [&](int xs) {
    return bf_bytes + (size_t)xs * B_ * M_ * NJ * 2 * sizeof(float);
  };
  int XS = 8;
  if (ws_size < need(8)) XS = 4;
  if (ws_size < need(4)) XS = 2;
  if (ws_size < need(2)) XS = 1;
  float* partial = (float*)((char*)d_ws + bf_bytes);

  {
    int total = B_*X_*KS*NF*64*8;   // 491,520
    prep_bfrag<<<(total + 255)/256, 256, 0, stream>>>(xin, maps, Bf);
  }
  {
    dim3 g(M_/128, XS, B_);
    main_mfma<<<g, 256, 0, stream>>>(coord, Bf, partial, XS, X_/XS);
  }
  {
    int total = B_*M_*C_;           // 65,536
    combine2<<<(total + 255)/256, 256, 0, stream>>>(partial, phi, out, XS);
  }
}